// Round 9
// baseline (719.143 us; speedup 1.0000x reference)
//
#include <hip/hip_runtime.h>

// ---------------------------------------------------------------------------
// ZSSR involution net, fp32. Round 24 = R23 body (1x4 einsum, 173.9us) with
// the 6 e-layers fused into ONE cooperative kernel using PER-TILE DATAFLOW
// FLAGS (not grid barriers: R18/R20 showed any global convergence costs
// ~65us in XCD coherence). WG (T,g) after layer l release-increments
// cnt[l][T] (4 incr/counter, 64B stride, uncontended); before layer l+1 it
// polls its 3x3 neighborhood counters to 4 (covers x-halo + t-partial deps),
// then acquires. Layers execute as a wavefront; no convergence point.
// WAR across layers eliminated via per-layer buffers: x0..x6 + t0..t5
// (~59MB of workspace; fills show >=256MB available). Deadlock-free:
// acyclic deps + cooperative residency (1184 <= 1280 @ 5WG/CU, 26768B LDS).
// Fallback: R23 6-dispatch path on the same per-layer buffers.
// Layout: x[4 g][136x136 px][16 ch] channel-last, 3-px zero border.
// ---------------------------------------------------------------------------

#define HH 130
#define SP 136               // padded row stride
#define PPL (SP*SP)          // 18496
#define GP (PPL*16)          // floats per group-plane
#define XBUF2 ((size_t)4*GP)         // floats per feature buffer (4.73MB)
#define TP1 (16900*16)               // one group-partial buffer [px][16]
#define TSET ((size_t)4*TP1)         // one layer's t set (4 groups)
#define NT 296                       // flag slots per layer (T<289 used)
#define OFF_X(l)  ((size_t)(l)*XBUF2)            // x0..x6
#define OFF_TS(l) ((size_t)7*XBUF2 + (size_t)(l)*TSET)   // t0..t5
#define OFF_FLAG  ((size_t)7*XBUF2 + (size_t)6*TSET)     // cnt[5][296] @64B

// --- conv_in (3->64, 3x3, pad=2) + border zero x0..x6 + flags + t0 ---------
__global__ __launch_bounds__(256) void conv_in_kernel(
        const float* __restrict__ inf, const float* __restrict__ W,
        const float* __restrict__ b, float* __restrict__ ws,
        const float* __restrict__ redw0) {   // [16][64] layer 0
    const int tid = threadIdx.x;
    if (blockIdx.x >= 67) {
        if (blockIdx.x == 67 && blockIdx.y == 0) {
            unsigned* flg = (unsigned*)(ws + OFF_FLAG);
            for (int i = tid; i < 5*NT; i += 256) flg[i*16] = 0u;
        }
        int idx = ((blockIdx.x - 67)*4 + blockIdx.y)*256 + tid;
        if (idx < 1596*7) {                    // border px x 7 buffers
            int bsel = idx % 7, e = idx / 7;
            int r, c;
            if (e < 816) { r = e/136; c = e%136; if (r >= 3) r += 130; }
            else { int j = e-816; r = 3 + j/6; int m = j%6; c = (m<3)? m : m+130; }
            float* base = ws + OFF_X(bsel) + ((size_t)r*SP + c)*16;
            float4 z = make_float4(0.f,0.f,0.f,0.f);
            #pragma unroll
            for (int g2 = 0; g2 < 4; ++g2)
                #pragma unroll
                for (int q = 0; q < 4; ++q)
                    *(float4*)(base + (size_t)g2*GP + q*4) = z;
        }
        return;
    }
    __shared__ float wl[448];          // [16 ch][27 taps] + bias[16]
    const int g = blockIdx.y;
    for (int i = tid; i < 448; i += 256)
        wl[i] = (i < 432) ? W[g*432 + i] : b[g*16 + (i-432)];
    __syncthreads();
    int px = blockIdx.x*256 + tid;
    int pxc = px < 16900 ? px : 16899;
    int h = pxc/130, w = pxc%130;
    float xv[27];
    #pragma unroll
    for (int i = 0; i < 3; ++i)
      #pragma unroll
      for (int ky = 0; ky < 3; ++ky) {
        int y = h - 2 + ky;
        #pragma unroll
        for (int kx = 0; kx < 3; ++kx) {
            int xx = w - 2 + kx;
            float v = 0.f;
            if ((unsigned)y < 128u && (unsigned)xx < 128u)
                v = inf[i*16384 + y*128 + xx];
            xv[i*9 + ky*3 + kx] = v;
        }
      }
    float acc[16];
    #pragma unroll
    for (int c = 0; c < 16; ++c) {
        float a = wl[432 + c];
        #pragma unroll
        for (int t = 0; t < 27; ++t) a += wl[c*27 + t] * xv[t];
        acc[c] = a;
    }
    if (px < 16900) {
        float* dst = ws + OFF_X(0) + (size_t)g*GP
                     + ((size_t)(h+3)*SP + (w+3))*16;
        #pragma unroll
        for (int q = 0; q < 4; ++q)
            *(float4*)(dst + q*4) =
                make_float4(acc[q*4], acc[q*4+1], acc[q*4+2], acc[q*4+3]);
        // layer-0 t partial for group g (thread owns all 16 ch; s_load redw0)
        float* td = ws + OFF_TS(0) + (size_t)g*TP1 + (size_t)px*16;
        #pragma unroll
        for (int rq = 0; rq < 4; ++rq) {
            float p0=0.f, p1=0.f, p2=0.f, p3=0.f;
            #pragma unroll
            for (int j = 0; j < 16; ++j) {
                float a = acc[j];
                p0 += redw0[(rq*4+0)*64 + g*16 + j]*a;
                p1 += redw0[(rq*4+1)*64 + g*16 + j]*a;
                p2 += redw0[(rq*4+2)*64 + g*16 + j]*a;
                p3 += redw0[(rq*4+3)*64 + g*16 + j]*a;
            }
            *(float4*)(td + rq*4) = make_float4(p0, p1, p2, p3);
        }
    }
}

// ---------------------------------------------------------------------------
// Layer body = R23 e_kernel v16 (1x4-px einsum, one wave).
// LDS: xl[4][14][15][4] 13440B + uu (tl[64][20] ALIAS wl[49][68]) 13328B
//    = 26768B -> 5 WG/CU at launch_bounds(256,5).
#define TL(p, r)  uu[(p)*20 + (r)]
#define WLK(k, p) uu[(k)*68 + (p)]

__device__ __forceinline__ void inv_layer_body(
        float (*xl)[14][15][4], float* uu,
        const int T, const int g, const int ty, const int tx,
        const int tid, const int px, const int wv, const int sr, const int sc,
        const float* __restrict__ x,
        const float* __restrict__ tread,
        float* __restrict__ twrite,
        const float* __restrict__ gamma, const float* __restrict__ beta,
        const float* __restrict__ spanw, const float* __restrict__ spanb,
        const float* __restrict__ redwn,
        float* __restrict__ xout,
        const int doNext)
{
    // ---- stage halo: 14x14 px, 4 quads (group g's 16 ch) ----
    for (int i = tid; i < 784; i += 256) {
        int q = i & 3, p = i >> 2;
        int r = p / 14, c = p % 14;
        int gr = ty + r, gc = tx + c;
        gr = gr < SP ? gr : SP-1;          // clamp lands in zero border
        gc = gc < SP ? gc : SP-1;
        float4 v = *(const float4*)(x + (size_t)g*GP
                                    + ((size_t)gr*SP + gc)*16 + q*4);
        *(float4*)&xl[q][r][c][0] = v;
    }

    // ---- t dedup: thread (px,wv) sums r-quad wv across the 4 partials ----
    const int hh = min(ty + sr, HH-1), ww = min(tx + sc, HH-1);
    {
        const size_t toff = ((size_t)hh*HH + ww)*16 + wv*4;
        float4 s = make_float4(0.f,0.f,0.f,0.f);
        #pragma unroll
        for (int gg = 0; gg < 4; ++gg) {
            float4 a = *(const float4*)(tread + (size_t)gg*TP1 + toff);
            s.x += a.x; s.y += a.y; s.z += a.z; s.w += a.w;
        }
        *(float4*)&TL(px, wv*4) = s;       // raw sums (BN applied on read)
    }
    __syncthreads();                       // #1: tl complete

    // ---- read t16 (BN+ReLU) ----
    float t16[16];
    #pragma unroll
    for (int q = 0; q < 4; ++q) {
        float4 v = *(const float4*)&TL(px, q*4);
        t16[q*4+0] = fmaxf(gamma[q*4+0]*v.x + beta[q*4+0], 0.f);
        t16[q*4+1] = fmaxf(gamma[q*4+1]*v.y + beta[q*4+1], 0.f);
        t16[q*4+2] = fmaxf(gamma[q*4+2]*v.z + beta[q*4+2], 0.f);
        t16[q*4+3] = fmaxf(gamma[q*4+3]*v.w + beta[q*4+3], 0.f);
    }
    __syncthreads();                       // #2: tl reads done, wl may write

    // ---- w-gen: lane = pixel, wave = k-chunk (13/12/12/12) ----
    {
        const float* sw = spanw + g*784;   // k,r wave-uniform -> s_load
        const float* sb = spanb + g*49;
        const int k0 = wv ? (wv*12 + 1) : 0;
        #pragma unroll
        for (int j = 0; j < 12; ++j) {
            int k = k0 + j;
            float a = sb[k];
            #pragma unroll
            for (int r = 0; r < 16; ++r) a += sw[k*16 + r] * t16[r];
            WLK(k, px) = a;
        }
        if (wv == 0) {
            float a = sb[12];
            #pragma unroll
            for (int r = 0; r < 16; ++r) a += sw[12*16 + r] * t16[r];
            WLK(12, px) = a;
        }
    }
    __syncthreads();                       // #3: wl complete (and halo in xl)

    // ---- einsum: 1x4 px register blocking, ONE wave (tid<64) ----
    float4 o0 = make_float4(0.f,0.f,0.f,0.f);
    float4 o1 = o0, o2 = o0, o3 = o0;
    int px0 = 0, cq2 = 0;
    if (tid < 64) {
        cq2 = tid >> 4;
        const int pr = tid & 15;
        const int sr2 = pr >> 1, sc0 = (pr & 1)*4;
        px0 = sr2*8 + sc0;
        float4 a0 = make_float4(0.f,0.f,0.f,0.f);
        float4 a1 = a0, a2 = a0, a3 = a0;
        #pragma unroll
        for (int i = 0; i < 7; ++i) {
            float4 row[10];
            #pragma unroll
            for (int j = 0; j < 10; ++j)
                row[j] = *(const float4*)&xl[cq2][sr2 + i][sc0 + j][0];
            #pragma unroll
            for (int j = 0; j < 7; ++j) {
                float4 wp = *(const float4*)&WLK(i*7 + j, px0);
                a0.x += wp.x*row[j  ].x; a0.y += wp.x*row[j  ].y;
                a0.z += wp.x*row[j  ].z; a0.w += wp.x*row[j  ].w;
                a1.x += wp.y*row[j+1].x; a1.y += wp.y*row[j+1].y;
                a1.z += wp.y*row[j+1].z; a1.w += wp.y*row[j+1].w;
                a2.x += wp.z*row[j+2].x; a2.y += wp.z*row[j+2].y;
                a2.z += wp.z*row[j+2].z; a2.w += wp.z*row[j+2].w;
                a3.x += wp.w*row[j+3].x; a3.y += wp.w*row[j+3].y;
                a3.z += wp.w*row[j+3].z; a3.w += wp.w*row[j+3].w;
            }
        }
        o0 = make_float4(fmaxf(a0.x,0.f), fmaxf(a0.y,0.f),
                         fmaxf(a0.z,0.f), fmaxf(a0.w,0.f));
        o1 = make_float4(fmaxf(a1.x,0.f), fmaxf(a1.y,0.f),
                         fmaxf(a1.z,0.f), fmaxf(a1.w,0.f));
        o2 = make_float4(fmaxf(a2.x,0.f), fmaxf(a2.y,0.f),
                         fmaxf(a2.z,0.f), fmaxf(a2.w,0.f));
        o3 = make_float4(fmaxf(a3.x,0.f), fmaxf(a3.y,0.f),
                         fmaxf(a3.z,0.f), fmaxf(a3.w,0.f));
        const int h2 = ty + sr2, w2 = tx + sc0;
        if (h2 < HH) {
            float* ob = xout + (size_t)g*GP
                        + ((size_t)(h2+3)*SP + (w2+3))*16 + cq2*4;
            if (w2   < HH) *(float4*)(ob)      = o0;
            if (w2+1 < HH) *(float4*)(ob + 16) = o1;
            if (w2+2 < HH) *(float4*)(ob + 32) = o2;
            if (w2+3 < HH) *(float4*)(ob + 48) = o3;
        }
    }

    // ---- next-layer t partial: in-WG reduce via dead xl, plain stores -----
    if (doNext) {
        float* ol = (float*)xl;            // [64][17]
        __syncthreads();                   // einsum reads of xl done
        if (tid < 64) {
            #pragma unroll
            for (int e = 0; e < 4; ++e) {
                ol[(px0+0)*17 + cq2*4 + e] = (&o0.x)[e];
                ol[(px0+1)*17 + cq2*4 + e] = (&o1.x)[e];
                ol[(px0+2)*17 + cq2*4 + e] = (&o2.x)[e];
                ol[(px0+3)*17 + cq2*4 + e] = (&o3.x)[e];
            }
        }
        __syncthreads();
        // thread (px, rq = wv): partial t rows rq*4..+3 over group's 16 ch
        const int rq = wv;
        float p0=0.f, p1=0.f, p2=0.f, p3=0.f;
        #pragma unroll
        for (int j = 0; j < 16; ++j) {
            float xv = ol[px*17 + j];
            const int c = g*16 + j;        // wave-uniform -> s_load redwn
            p0 += redwn[(rq*4+0)*64 + c]*xv;
            p1 += redwn[(rq*4+1)*64 + c]*xv;
            p2 += redwn[(rq*4+2)*64 + c]*xv;
            p3 += redwn[(rq*4+3)*64 + c]*xv;
        }
        const int hR = ty + sr, wR = tx + sc;
        if (hR < HH && wR < HH)
            *(float4*)(twrite + (size_t)g*TP1
                       + ((size_t)hR*HH + wR)*16 + rq*4) =
                make_float4(p0, p1, p2, p3);
    }
}

// --- fused 6-layer cooperative kernel, per-tile dataflow flags -------------
__global__ __launch_bounds__(256, 5) void e_all_kernel(
        float* __restrict__ ws,
        const float* __restrict__ gam, const float* __restrict__ bet,
        const float* __restrict__ spw, const float* __restrict__ spb,
        const float* __restrict__ redw)
{
    __shared__ float xl[4][14][15][4];
    __shared__ float uu[49*68];
    const int wid = blockIdx.x;
    const int slot = wid >> 3;
    const int T = (wid & 7)*37 + (slot >> 2);
    if (T >= 289) return;
    const int g = slot & 3;
    const int ty = (T/17)*8, tx = (T%17)*8;
    const int tid = threadIdx.x;
    const int px = tid & 63;
    const int wv = __builtin_amdgcn_readfirstlane(tid >> 6);
    const int sr = px >> 3, sc = px & 7;
    const int Tr = T/17, Tc = T%17;
    unsigned* flg = (unsigned*)(ws + OFF_FLAG);

    for (int l = 0; l < 6; ++l) {
        if (l > 0) {
            if (tid == 0) {
                #pragma unroll
                for (int dr = -1; dr <= 1; ++dr)
                    #pragma unroll
                    for (int dc = -1; dc <= 1; ++dc) {
                        int rr = Tr + dr, cc = Tc + dc;
                        if ((unsigned)rr < 17u && (unsigned)cc < 17u) {
                            unsigned* f = flg
                                + (((size_t)(l-1)*NT + rr*17 + cc) << 4);
                            while (__hip_atomic_load(f, __ATOMIC_RELAXED,
                                       __HIP_MEMORY_SCOPE_AGENT) < 4u)
                                __builtin_amdgcn_s_sleep(1);
                            (void)__hip_atomic_load(f, __ATOMIC_ACQUIRE,
                                       __HIP_MEMORY_SCOPE_AGENT);
                        }
                    }
            }
            __syncthreads();               // all threads gated on flags
        }
        const int doNext = (l < 5);
        const int lt = doNext ? (l + 1) : 5;   // twrite unused when !doNext
        inv_layer_body(xl, uu, T, g, ty, tx, tid, px, wv, sr, sc,
                       ws + OFF_X(l), ws + OFF_TS(l), ws + OFF_TS(lt),
                       gam + l*16, bet + l*16,
                       spw + l*3136, spb + l*196,
                       redw + (doNext ? (l+1)*1024 : 0),
                       ws + OFF_X(l+1), doNext);
        if (l < 5) {
            __syncthreads();               // drain this WG's stores (vmcnt0)
            if (tid == 0)
                __hip_atomic_fetch_add(flg + (((size_t)l*NT + T) << 4), 1u,
                                       __ATOMIC_RELEASE,
                                       __HIP_MEMORY_SCOPE_AGENT);
        }
    }
}

// --- fallback per-layer kernel (R23 behavior, per-layer buffers) -----------
__global__ __launch_bounds__(256, 5) void e_kernel(
        const float* __restrict__ x,
        const float* __restrict__ tread,
        float* __restrict__ twrite,
        const float* __restrict__ gamma, const float* __restrict__ beta,
        const float* __restrict__ spanw,
        const float* __restrict__ spanb,
        const float* __restrict__ redwn,
        float* __restrict__ xout,
        const int doNext)
{
    __shared__ float xl[4][14][15][4];
    __shared__ float uu[49*68];
    const int wid = blockIdx.x;
    const int slot = wid >> 3;
    const int T = (wid & 7)*37 + (slot >> 2);
    if (T >= 289) return;
    const int g = slot & 3;
    const int ty = (T/17)*8, tx = (T%17)*8;
    const int tid = threadIdx.x;
    const int px = tid & 63;
    const int wv = __builtin_amdgcn_readfirstlane(tid >> 6);
    const int sr = px >> 3, sc = px & 7;
    inv_layer_body(xl, uu, T, g, ty, tx, tid, px, wv, sr, sc,
                   x, tread, twrite, gamma, beta, spanw, spanb, redwn,
                   xout, doNext);
}

// --- conv_out (64->12, 3x3 valid) + PixelShuffle(2) ------------------------
__global__ __launch_bounds__(256) void conv_out_ps_kernel(
        const float* __restrict__ x, const float* __restrict__ W,
        const float* __restrict__ b, float* __restrict__ out)
{
    __shared__ float xh[64*120];   // [c][10 r][12 cl]
    __shared__ float wl[6912];     // 12*64*9
    const int tid = threadIdx.x;
    const int ty = blockIdx.y*8, tx = blockIdx.x*8;

    for (int idx = tid; idx < 6912; idx += 256) wl[idx] = W[idx];
    for (int idx = tid; idx < 1600; idx += 256) {
        int g = idx/400, rem = idx%400;
        int p100 = rem>>2, q = rem&3;
        int r = p100/10, cl = p100%10;
        float4 v = *(const float4*)(x + (size_t)g*GP
                     + ((size_t)(ty + r + 3)*SP + tx + cl + 3)*16 + q*4);
        int c0 = g*16 + q*4;
        xh[(c0+0)*120 + r*12 + cl] = v.x;
        xh[(c0+1)*120 + r*12 + cl] = v.y;
        xh[(c0+2)*120 + r*12 + cl] = v.z;
        xh[(c0+3)*120 + r*12 + cl] = v.w;
    }
    __syncthreads();

    const int wave = __builtin_amdgcn_readfirstlane(tid >> 6);
    const int lane = tid & 63;
    const int s = lane >> 2, cq = lane & 3;
    const int sr = s >> 1, pc0 = (s & 1)*4;
    float acc[3][4] = {};

    for (int c = cq*16; c < cq*16 + 16; ++c) {
        #pragma unroll
        for (int ky = 0; ky < 3; ++ky) {
            const float* xb = &xh[c*120 + (sr + ky)*12 + pc0];
            float4 xa = *(const float4*)xb;
            float2 xm = *(const float2*)(xb + 4);
            float xr[6] = {xa.x, xa.y, xa.z, xa.w, xm.x, xm.y};
            #pragma unroll
            for (int oj = 0; oj < 3; ++oj) {
                const float* wp = &wl[((wave*3 + oj)*64 + c)*9 + ky*3];
                #pragma unroll
                for (int kx = 0; kx < 3; ++kx) {
                    float wv = wp[kx];
                    #pragma unroll
                    for (int q = 0; q < 4; ++q)
                        acc[oj][q] += wv * xr[kx + q];
                }
            }
        }
    }

    #pragma unroll
    for (int oj = 0; oj < 3; ++oj)
        #pragma unroll
        for (int q = 0; q < 4; ++q) {
            float v = acc[oj][q];
            v += __shfl_xor(v, 1, 64);
            v += __shfl_xor(v, 2, 64);
            acc[oj][q] = v;
        }

    if (cq == 0) {
        #pragma unroll
        for (int oj = 0; oj < 3; ++oj) {
            int o = wave*3 + oj;
            float bo = b[o];
            int c3 = o >> 2, r = (o >> 1) & 1, s2 = o & 1;
            int h = ty + sr;
            #pragma unroll
            for (int q = 0; q < 4; ++q) {
                int w = tx + pc0 + q;
                out[c3*65536 + (2*h + r)*256 + 2*w + s2] = acc[oj][q] + bo;
            }
        }
    }
}

// ---------------------------------------------------------------------------
extern "C" void kernel_launch(void* const* d_in, const int* in_sizes, int n_in,
                              void* d_out, int out_size, void* d_ws, size_t ws_size,
                              hipStream_t stream) {
    const float* inf   = (const float*)d_in[0];
    const float* cinw  = (const float*)d_in[1];
    const float* cinb  = (const float*)d_in[2];
    const float* redw  = (const float*)d_in[3];
    const float* gam   = (const float*)d_in[4];
    const float* bet   = (const float*)d_in[5];
    const float* spw   = (const float*)d_in[6];
    const float* spb   = (const float*)d_in[7];
    const float* cow   = (const float*)d_in[8];
    const float* cob   = (const float*)d_in[9];

    float* ws = (float*)d_ws;

    conv_in_kernel<<<dim3(80, 4), 256, 0, stream>>>(
        inf, cinw, cinb, ws, redw);

    void* args[] = { (void*)&ws, (void*)&gam, (void*)&bet,
                     (void*)&spw, (void*)&spb, (void*)&redw };
    hipError_t ce = hipLaunchCooperativeKernel(
        (const void*)e_all_kernel, dim3(1184), dim3(256), args, 0, stream);

    if (ce != hipSuccess) {
        for (int l = 0; l < 6; ++l) {
            const int doNext = (l < 5);
            const int lt = doNext ? (l + 1) : 5;
            e_kernel<<<1184, 256, 0, stream>>>(
                ws + OFF_X(l), ws + OFF_TS(l), ws + OFF_TS(lt),
                gam + l*16, bet + l*16,
                spw + l*3136, spb + l*196,
                redw + (doNext ? (l+1)*1024 : 0),
                ws + OFF_X(l+1), doNext);
        }
    }

    conv_out_ps_kernel<<<dim3(16, 16), 256, 0, stream>>>(
        ws + OFF_X(6), cow, cob, (float*)d_out);
}

// Round 10
// 172.912 us; speedup vs baseline: 4.1590x; 4.1590x over previous
//
#include <hip/hip_runtime.h>

// ---------------------------------------------------------------------------
// ZSSR involution net, fp32. Round 25 = terminal revert to R23 (173.9us,
// session best). Structure: conv_in + 6x e_kernel (v16: 1x4-px einsum) +
// conv_out. Final lever audit:
//  - einsum DS cuts: R16 +13.6us, R23 +1.4us (diminishing; body is
//    phase-latency-bound, not DS-throughput-bound)
//  - occupancy 5 vs 6 WG/CU: exactly 0 (R22)
//  - tile 16x8 @3WG: -43us (R19); global-direct einsum: -69us (R21)
//  - fusion: grid.sync -160us/sync (R17); custom barrier -65us/sync (R18);
//    tree barrier identical (R20); dataflow flags ~same + L2 blowup (R24).
//    Cross-WG sync on MI355X costs ~10x a dispatch boundary (XCD coherence).
// Budget at 173.9us: ~83 harness fills + ~8 conv_in + ~72 e-dispatches
// (~6.3 body + ~5.7 boundary each) + ~5 conv_out + ~6 edges. Structural
// floor within a few percent.
// Layout: x[4 g][136x136 px][16 ch] channel-last, 3-px zero border.
// ---------------------------------------------------------------------------

#define HH 130
#define SP 136               // padded row stride
#define PPL (SP*SP)          // 18496
#define GP (PPL*16)          // floats per group-plane
#define XBUF2 (4*GP)         // floats per feature buffer
#define TP1 (16900*16)       // one group-partial buffer [px][16]
#define OFF_TA (2*XBUF2)             // set A: 4 buffers
#define OFF_TB (OFF_TA + 4*TP1)      // set B: 4 buffers

// --- conv_in (3->64, 3x3, pad=2) + border zeroing + layer-0 t partials -----
__global__ __launch_bounds__(256) void conv_in_kernel(
        const float* __restrict__ inf, const float* __restrict__ W,
        const float* __restrict__ b, float* __restrict__ x0,
        float* __restrict__ x1, float* __restrict__ tpA,
        const float* __restrict__ redw0) {   // [16][64] layer 0
    const int tid = threadIdx.x;
    if (blockIdx.x >= 67) {
        int idx = ((blockIdx.x - 67)*4 + blockIdx.y)*256 + tid;
        if (idx < 3192) {                      // 1596 border px * 2 buffers
            int bsel = idx & 1, e = idx >> 1;
            int r, c;
            if (e < 816) { r = e/136; c = e%136; if (r >= 3) r += 130; }
            else { int j = e-816; r = 3 + j/6; int m = j%6; c = (m<3)? m : m+130; }
            float* base = (bsel ? x1 : x0) + ((size_t)r*SP + c)*16;
            float4 z = make_float4(0.f,0.f,0.f,0.f);
            #pragma unroll
            for (int g2 = 0; g2 < 4; ++g2)
                #pragma unroll
                for (int q = 0; q < 4; ++q)
                    *(float4*)(base + (size_t)g2*GP + q*4) = z;
        }
        return;
    }
    __shared__ float wl[448];          // [16 ch][27 taps] + bias[16]
    const int g = blockIdx.y;
    for (int i = tid; i < 448; i += 256)
        wl[i] = (i < 432) ? W[g*432 + i] : b[g*16 + (i-432)];
    __syncthreads();
    int px = blockIdx.x*256 + tid;
    int pxc = px < 16900 ? px : 16899;
    int h = pxc/130, w = pxc%130;
    float xv[27];
    #pragma unroll
    for (int i = 0; i < 3; ++i)
      #pragma unroll
      for (int ky = 0; ky < 3; ++ky) {
        int y = h - 2 + ky;
        #pragma unroll
        for (int kx = 0; kx < 3; ++kx) {
            int xx = w - 2 + kx;
            float v = 0.f;
            if ((unsigned)y < 128u && (unsigned)xx < 128u)
                v = inf[i*16384 + y*128 + xx];
            xv[i*9 + ky*3 + kx] = v;
        }
      }
    float acc[16];
    #pragma unroll
    for (int c = 0; c < 16; ++c) {
        float a = wl[432 + c];
        #pragma unroll
        for (int t = 0; t < 27; ++t) a += wl[c*27 + t] * xv[t];
        acc[c] = a;
    }
    if (px < 16900) {
        float* dst = x0 + (size_t)g*GP + ((size_t)(h+3)*SP + (w+3))*16;
        #pragma unroll
        for (int q = 0; q < 4; ++q)
            *(float4*)(dst + q*4) =
                make_float4(acc[q*4], acc[q*4+1], acc[q*4+2], acc[q*4+3]);
        // layer-0 t partial for group g (thread owns all 16 ch; s_load redw0)
        float* td = tpA + (size_t)g*TP1 + (size_t)px*16;
        #pragma unroll
        for (int rq = 0; rq < 4; ++rq) {
            float p0=0.f, p1=0.f, p2=0.f, p3=0.f;
            #pragma unroll
            for (int j = 0; j < 16; ++j) {
                float a = acc[j];
                p0 += redw0[(rq*4+0)*64 + g*16 + j]*a;
                p1 += redw0[(rq*4+1)*64 + g*16 + j]*a;
                p2 += redw0[(rq*4+2)*64 + g*16 + j]*a;
                p3 += redw0[(rq*4+3)*64 + g*16 + j]*a;
            }
            *(float4*)(td + rq*4) = make_float4(p0, p1, p2, p3);
        }
    }
}

// --- e_kernel v16: 1x4-px einsum (one wave) --------------------------------
// grid 1184: wid&7 = band, slot = wid>>3; T = band*37+(slot>>2), g = slot&3.
// LDS: xl[4][14][15][4] 13440B + uu (tl[64][20] ALIAS wl[49][68]) 13328B
//    = 26768B -> 5 WG/CU at launch_bounds(256,5).
#define TL(p, r)  uu[(p)*20 + (r)]
#define WLK(k, p) uu[(k)*68 + (p)]
__global__ __launch_bounds__(256, 5) void e_kernel(
        const float* __restrict__ x,
        const float* __restrict__ tread,  // 4 partial bufs, this layer
        float* __restrict__ twrite,       // 4 partial bufs, next layer
        const float* __restrict__ gamma, const float* __restrict__ beta,
        const float* __restrict__ spanw,  // [4 g][49 k][16 r]
        const float* __restrict__ spanb,  // [4 g][49]
        const float* __restrict__ redwn,  // [16][64] next layer
        float* __restrict__ xout,
        const int doNext)
{
    __shared__ float xl[4][14][15][4];
    __shared__ float uu[49*68];           // tl (phase 1) then wl (phase 2)
    const int wid = blockIdx.x;
    const int slot = wid >> 3;
    const int T = (wid & 7)*37 + (slot >> 2);
    if (T >= 289) return;
    const int g = slot & 3;
    const int ty = (T/17)*8, tx = (T%17)*8;
    const int tid = threadIdx.x;
    const int px = tid & 63;
    const int wv = __builtin_amdgcn_readfirstlane(tid >> 6);
    const int sr = px >> 3, sc = px & 7;

    // ---- stage halo: 14x14 px, 4 quads (group g's 16 ch) ----
    for (int i = tid; i < 784; i += 256) {
        int q = i & 3, p = i >> 2;
        int r = p / 14, c = p % 14;
        int gr = ty + r, gc = tx + c;
        gr = gr < SP ? gr : SP-1;          // clamp lands in zero border
        gc = gc < SP ? gc : SP-1;
        float4 v = *(const float4*)(x + (size_t)g*GP
                                    + ((size_t)gr*SP + gc)*16 + q*4);
        *(float4*)&xl[q][r][c][0] = v;
    }

    // ---- t dedup: thread (px,wv) sums r-quad wv across the 4 partials ----
    const int hh = min(ty + sr, HH-1), ww = min(tx + sc, HH-1);
    {
        const size_t toff = ((size_t)hh*HH + ww)*16 + wv*4;
        float4 s = make_float4(0.f,0.f,0.f,0.f);
        #pragma unroll
        for (int gg = 0; gg < 4; ++gg) {
            float4 a = *(const float4*)(tread + (size_t)gg*TP1 + toff);
            s.x += a.x; s.y += a.y; s.z += a.z; s.w += a.w;
        }
        *(float4*)&TL(px, wv*4) = s;       // raw sums (BN applied on read)
    }
    __syncthreads();                       // #1: tl complete

    // ---- read t16 (BN+ReLU) ----
    float t16[16];
    #pragma unroll
    for (int q = 0; q < 4; ++q) {
        float4 v = *(const float4*)&TL(px, q*4);
        t16[q*4+0] = fmaxf(gamma[q*4+0]*v.x + beta[q*4+0], 0.f);
        t16[q*4+1] = fmaxf(gamma[q*4+1]*v.y + beta[q*4+1], 0.f);
        t16[q*4+2] = fmaxf(gamma[q*4+2]*v.z + beta[q*4+2], 0.f);
        t16[q*4+3] = fmaxf(gamma[q*4+3]*v.w + beta[q*4+3], 0.f);
    }
    __syncthreads();                       // #2: tl reads done, wl may write

    // ---- w-gen: lane = pixel, wave = k-chunk (13/12/12/12) ----
    {
        const float* sw = spanw + g*784;   // k,r wave-uniform -> s_load
        const float* sb = spanb + g*49;
        const int k0 = wv ? (wv*12 + 1) : 0;
        #pragma unroll
        for (int j = 0; j < 12; ++j) {
            int k = k0 + j;
            float a = sb[k];
            #pragma unroll
            for (int r = 0; r < 16; ++r) a += sw[k*16 + r] * t16[r];
            WLK(k, px) = a;
        }
        if (wv == 0) {
            float a = sb[12];
            #pragma unroll
            for (int r = 0; r < 16; ++r) a += sw[12*16 + r] * t16[r];
            WLK(12, px) = a;
        }
    }
    __syncthreads();                       // #3: wl complete (and halo in xl)

    // ---- einsum: 1x4 px register blocking, ONE wave (tid<64) ----
    // cq2 = tid>>4 (quad), pr = tid&15: sr2 = pr>>1, sc0 = (pr&1)*4.
    // Per window row: 10-wide float4 strip read once, slid across 4 px;
    // weights for px0..px0+3 come as one b128 (16B-aligned: stride 68).
    float4 o0 = make_float4(0.f,0.f,0.f,0.f);
    float4 o1 = o0, o2 = o0, o3 = o0;
    int px0 = 0, cq2 = 0;
    if (tid < 64) {
        cq2 = tid >> 4;
        const int pr = tid & 15;
        const int sr2 = pr >> 1, sc0 = (pr & 1)*4;
        px0 = sr2*8 + sc0;
        float4 a0 = make_float4(0.f,0.f,0.f,0.f);
        float4 a1 = a0, a2 = a0, a3 = a0;
        #pragma unroll
        for (int i = 0; i < 7; ++i) {
            float4 row[10];
            #pragma unroll
            for (int j = 0; j < 10; ++j)
                row[j] = *(const float4*)&xl[cq2][sr2 + i][sc0 + j][0];
            #pragma unroll
            for (int j = 0; j < 7; ++j) {
                float4 wp = *(const float4*)&WLK(i*7 + j, px0);
                a0.x += wp.x*row[j  ].x; a0.y += wp.x*row[j  ].y;
                a0.z += wp.x*row[j  ].z; a0.w += wp.x*row[j  ].w;
                a1.x += wp.y*row[j+1].x; a1.y += wp.y*row[j+1].y;
                a1.z += wp.y*row[j+1].z; a1.w += wp.y*row[j+1].w;
                a2.x += wp.z*row[j+2].x; a2.y += wp.z*row[j+2].y;
                a2.z += wp.z*row[j+2].z; a2.w += wp.z*row[j+2].w;
                a3.x += wp.w*row[j+3].x; a3.y += wp.w*row[j+3].y;
                a3.z += wp.w*row[j+3].z; a3.w += wp.w*row[j+3].w;
            }
        }
        o0 = make_float4(fmaxf(a0.x,0.f), fmaxf(a0.y,0.f),
                         fmaxf(a0.z,0.f), fmaxf(a0.w,0.f));
        o1 = make_float4(fmaxf(a1.x,0.f), fmaxf(a1.y,0.f),
                         fmaxf(a1.z,0.f), fmaxf(a1.w,0.f));
        o2 = make_float4(fmaxf(a2.x,0.f), fmaxf(a2.y,0.f),
                         fmaxf(a2.z,0.f), fmaxf(a2.w,0.f));
        o3 = make_float4(fmaxf(a3.x,0.f), fmaxf(a3.y,0.f),
                         fmaxf(a3.z,0.f), fmaxf(a3.w,0.f));
        const int h2 = ty + sr2, w2 = tx + sc0;
        if (h2 < HH) {
            float* ob = xout + (size_t)g*GP
                        + ((size_t)(h2+3)*SP + (w2+3))*16 + cq2*4;
            if (w2   < HH) *(float4*)(ob)      = o0;
            if (w2+1 < HH) *(float4*)(ob + 16) = o1;
            if (w2+2 < HH) *(float4*)(ob + 32) = o2;
            if (w2+3 < HH) *(float4*)(ob + 48) = o3;
        }
    }

    // ---- next-layer t partial: in-WG reduce via dead xl, plain stores -----
    if (doNext) {
        float* ol = (float*)xl;            // [64][17]
        __syncthreads();                   // einsum reads of xl done
        if (tid < 64) {
            #pragma unroll
            for (int e = 0; e < 4; ++e) {
                ol[(px0+0)*17 + cq2*4 + e] = (&o0.x)[e];
                ol[(px0+1)*17 + cq2*4 + e] = (&o1.x)[e];
                ol[(px0+2)*17 + cq2*4 + e] = (&o2.x)[e];
                ol[(px0+3)*17 + cq2*4 + e] = (&o3.x)[e];
            }
        }
        __syncthreads();
        // thread (px, rq = wv): partial t rows rq*4..+3 over group's 16 ch
        const int rq = wv;
        float p0=0.f, p1=0.f, p2=0.f, p3=0.f;
        #pragma unroll
        for (int j = 0; j < 16; ++j) {
            float xv = ol[px*17 + j];
            const int c = g*16 + j;        // wave-uniform -> s_load redwn
            p0 += redwn[(rq*4+0)*64 + c]*xv;
            p1 += redwn[(rq*4+1)*64 + c]*xv;
            p2 += redwn[(rq*4+2)*64 + c]*xv;
            p3 += redwn[(rq*4+3)*64 + c]*xv;
        }
        const int hR = ty + sr, wR = tx + sc;
        if (hR < HH && wR < HH)
            *(float4*)(twrite + (size_t)g*TP1
                       + ((size_t)hR*HH + wR)*16 + rq*4) =
                make_float4(p0, p1, p2, p3);
    }
}

// --- conv_out (64->12, 3x3 valid) + PixelShuffle(2) ------------------------
__global__ __launch_bounds__(256) void conv_out_ps_kernel(
        const float* __restrict__ x, const float* __restrict__ W,
        const float* __restrict__ b, float* __restrict__ out)
{
    __shared__ float xh[64*120];   // [c][10 r][12 cl]
    __shared__ float wl[6912];     // 12*64*9
    const int tid = threadIdx.x;
    const int ty = blockIdx.y*8, tx = blockIdx.x*8;

    for (int idx = tid; idx < 6912; idx += 256) wl[idx] = W[idx];
    for (int idx = tid; idx < 1600; idx += 256) {
        int g = idx/400, rem = idx%400;
        int p100 = rem>>2, q = rem&3;
        int r = p100/10, cl = p100%10;
        float4 v = *(const float4*)(x + (size_t)g*GP
                     + ((size_t)(ty + r + 3)*SP + tx + cl + 3)*16 + q*4);
        int c0 = g*16 + q*4;
        xh[(c0+0)*120 + r*12 + cl] = v.x;
        xh[(c0+1)*120 + r*12 + cl] = v.y;
        xh[(c0+2)*120 + r*12 + cl] = v.z;
        xh[(c0+3)*120 + r*12 + cl] = v.w;
    }
    __syncthreads();

    const int wave = __builtin_amdgcn_readfirstlane(tid >> 6);
    const int lane = tid & 63;
    const int s = lane >> 2, cq = lane & 3;
    const int sr = s >> 1, pc0 = (s & 1)*4;
    float acc[3][4] = {};

    for (int c = cq*16; c < cq*16 + 16; ++c) {
        #pragma unroll
        for (int ky = 0; ky < 3; ++ky) {
            const float* xb = &xh[c*120 + (sr + ky)*12 + pc0];
            float4 xa = *(const float4*)xb;
            float2 xm = *(const float2*)(xb + 4);
            float xr[6] = {xa.x, xa.y, xa.z, xa.w, xm.x, xm.y};
            #pragma unroll
            for (int oj = 0; oj < 3; ++oj) {
                const float* wp = &wl[((wave*3 + oj)*64 + c)*9 + ky*3];
                #pragma unroll
                for (int kx = 0; kx < 3; ++kx) {
                    float wv = wp[kx];
                    #pragma unroll
                    for (int q = 0; q < 4; ++q)
                        acc[oj][q] += wv * xr[kx + q];
                }
            }
        }
    }

    #pragma unroll
    for (int oj = 0; oj < 3; ++oj)
        #pragma unroll
        for (int q = 0; q < 4; ++q) {
            float v = acc[oj][q];
            v += __shfl_xor(v, 1, 64);
            v += __shfl_xor(v, 2, 64);
            acc[oj][q] = v;
        }

    if (cq == 0) {
        #pragma unroll
        for (int oj = 0; oj < 3; ++oj) {
            int o = wave*3 + oj;
            float bo = b[o];
            int c3 = o >> 2, r = (o >> 1) & 1, s2 = o & 1;
            int h = ty + sr;
            #pragma unroll
            for (int q = 0; q < 4; ++q) {
                int w = tx + pc0 + q;
                out[c3*65536 + (2*h + r)*256 + 2*w + s2] = acc[oj][q] + bo;
            }
        }
    }
}

// ---------------------------------------------------------------------------
extern "C" void kernel_launch(void* const* d_in, const int* in_sizes, int n_in,
                              void* d_out, int out_size, void* d_ws, size_t ws_size,
                              hipStream_t stream) {
    const float* inf   = (const float*)d_in[0];
    const float* cinw  = (const float*)d_in[1];
    const float* cinb  = (const float*)d_in[2];
    const float* redw  = (const float*)d_in[3];
    const float* gam   = (const float*)d_in[4];
    const float* bet   = (const float*)d_in[5];
    const float* spw   = (const float*)d_in[6];
    const float* spb   = (const float*)d_in[7];
    const float* cow   = (const float*)d_in[8];
    const float* cob   = (const float*)d_in[9];

    float* ws = (float*)d_ws;
    float* x0 = ws;
    float* x1 = ws + XBUF2;
    float* tA = ws + OFF_TA;
    float* tB = ws + OFF_TB;

    conv_in_kernel<<<dim3(80, 4), 256, 0, stream>>>(
        inf, cinw, cinb, x0, x1, tA, redw);

    float* cur = x0; float* nxt = x1;
    for (int l = 0; l < 6; ++l) {
        const int doNext = (l < 5);
        float* tread  = (l & 1) ? tB : tA;
        float* twrite = (l & 1) ? tA : tB;
        e_kernel<<<1184, 256, 0, stream>>>(
            cur, tread, twrite,
            gam + l*16, bet + l*16,
            spw + l*3136, spb + l*196,
            redw + (doNext ? (l+1)*1024 : 0),
            nxt, doNext);
        float* t = cur; cur = nxt; nxt = t;
    }

    conv_out_ps_kernel<<<dim3(16, 16), 256, 0, stream>>>(
        cur, cow, cob, (float*)d_out);
}